// Round 8
// baseline (1481.677 us; speedup 1.0000x reference)
//
#include <hip/hip_runtime.h>
#include <math.h>

#define T_DIM 8192
#define H_DIM 4096
#define I_DIM 11008

typedef int v4i  __attribute__((ext_vector_type(4)));
typedef int v16i __attribute__((ext_vector_type(16)));

#define MFMA8 __builtin_amdgcn_mfma_i32_32x32x32_i8

#define AS1(p) ((const __attribute__((address_space(1))) void*)(p))
#define AS3(p) ((__attribute__((address_space(3))) void*)(p))

// counted vmcnt wait + scheduler fence
#define WAITV(N) do { asm volatile("s_waitcnt vmcnt(" #N ")" ::: "memory"); \
                      __builtin_amdgcn_sched_barrier(0); } while (0)
#define BAR() __builtin_amdgcn_s_barrier()
// counted LDS wait + scheduler fence (rule #18)
#define LGKM(N) do { asm volatile("s_waitcnt lgkmcnt(" #N ")" ::: "memory"); \
                     __builtin_amdgcn_sched_barrier(0); } while (0)
#define SCHEDB() __builtin_amdgcn_sched_barrier(0)

__device__ __forceinline__ v4i DSR(const char* p) {
  v4i r;
  unsigned a = (unsigned)(size_t)(const __attribute__((address_space(3))) char*)p;
  asm volatile("ds_read_b128 %0, %1" : "=v"(r) : "v"(a));
  return r;
}

// wave-uniform pointer (forces SGPR materialization; r3-verified)
__device__ __forceinline__ const char* rflp(const void* p) {
  unsigned lo = __builtin_amdgcn_readfirstlane((unsigned)(unsigned long long)p);
  unsigned hi = __builtin_amdgcn_readfirstlane((unsigned)((unsigned long long)p >> 32));
  return (const char*)(((unsigned long long)hi << 32) | lo);
}

// One STG = one whole 1KB fragment per wave (wave-uniform LDS base + lane*16).
#define STG(ldst, gsrc) \
  __builtin_amdgcn_global_load_lds(AS1(gsrc), AS3(ldst), 16, 0, 0)

// ---------------- pack + shuffle into MFMA-fragment order (r3/r4-verified) ----
__global__ void pack_shuf(const int* __restrict__ src, char* __restrict__ dst,
                          int nk32, long nchunk) {
  long c = (long)blockIdx.x * blockDim.x + threadIdx.x;
  long stride = (long)gridDim.x * blockDim.x;
  for (; c < nchunk; c += stride) {
    int lane = (int)(c & 63);
    long rk = c >> 6;
    long r32 = rk / nk32;
    int k32 = (int)(rk - r32 * nk32);
    const int4* s = (const int4*)(src + (r32 * 32 + (lane & 31)) * (long)(nk32 * 32)
                                      + (long)k32 * 32 + ((lane >> 5) << 4));
    int4 a = s[0], b = s[1], cc = s[2], d = s[3];
    int w0 = (a.x & 255) | ((a.y & 255) << 8) | ((a.z & 255) << 16) | (a.w << 24);
    int w1 = (b.x & 255) | ((b.y & 255) << 8) | ((b.z & 255) << 16) | (b.w << 24);
    int w2 = (cc.x & 255) | ((cc.y & 255) << 8) | ((cc.z & 255) << 16) | (cc.w << 24);
    int w3 = (d.x & 255) | ((d.y & 255) << 8) | ((d.z & 255) << 16) | (d.w << 24);
    ((int4*)dst)[c] = make_int4(w0, w1, w2, w3);
  }
}

// ---------------- gate+up fused GEMM ----------------
// 256x128 tile, 8 waves (2M x 4N), wave = 128x32 x {gate,up}, BK=64.
// A via LDS (3x16KB bufs, distance-2 DMA, counted vmcnt); B (G/U) direct
// global->reg, distance-2 prefetch, ping-pong reg sets via unroll-2.
__global__ __launch_bounds__(512, 2) void gemm_gateup(
    const char* __restrict__ A, const char* __restrict__ Bg, const char* __restrict__ Bu,
    const float* __restrict__ ga_p, const float* __restrict__ gb,
    const float* __restrict__ ua_p, const float* __restrict__ ub,
    char* __restrict__ Q)
{
  __shared__ char lds[3][16384];
  const int tid = threadIdx.x;
  const int l = tid & 63;
  const int w = tid >> 6;          // 8 waves
  const int wm = w >> 2, wn = w & 3;
  const int li32 = l & 31, kg2 = l >> 5;

  // XCD-chunked bijection (nwg=2752, %8==0) + 4x2 supertile.
  const int q8 = 2752 / 8;
  int bid = blockIdx.x;
  int wgid = (bid & 7) * q8 + (bid >> 3);
  int st = wgid >> 3, r = wgid & 7;
  int sm = st / 43, sn = st - sm * 43;
  const int m0 = (sm * 4 + (r & 3)) * 256;
  const int n0 = (sn * 2 + (r >> 2)) * 128;

  const int NK = H_DIM / 32;   // 128 k32 blocks
  const int NT = H_DIM / 64;   // 64 K-tiles (BK=64)

  v16i accg[4], accu[4];
#pragma unroll
  for (int i = 0; i < 4; ++i)
#pragma unroll
    for (int j = 0; j < 16; ++j) { accg[i][j] = 0; accu[i][j] = 0; }

  const int lo = l * 16;
  // A staging: wave w stages frag (r32=(m0>>5)+w, ks=0/1) = 2 DMAs/tile.
  const char* pA0 = A + ((size_t)((m0 >> 5) + w) * NK) * 1024 + lo;   // ks=0 base
  const int dA0 = w * 2048 + lo;
  const int dA1 = dA0 + 1024;

#define STAGE_A(SB, tt)                                                   \
  do {                                                                    \
    size_t so = (size_t)(tt) * 2048;                                      \
    STG((SB) + dA0, pA0 + so);                                            \
    STG((SB) + dA1, pA0 + so + 1024);                                     \
  } while (0)

  // B bases (wave-uniform): G/U fragment column n32 = (n0>>5)+wn.
  const char* bG = rflp(Bg + ((size_t)((n0 >> 5) + wn) * NK) * 1024);
  const char* bU = rflp(Bu + ((size_t)((n0 >> 5) + wn) * NK) * 1024);

#define LDB_GU(G0, U0, G1, U1, tt)                                        \
  do {                                                                    \
    size_t ko = (size_t)(tt) * 2048 + lo;                                 \
    G0 = *(const v4i*)(bG + ko);        U0 = *(const v4i*)(bU + ko);      \
    G1 = *(const v4i*)(bG + ko + 1024); U1 = *(const v4i*)(bU + ko + 1024);\
    SCHEDB();                                                             \
  } while (0)

  const int oA0 = (wm * 4 + 0) * 2048 + lo;
  const int oA1 = (wm * 4 + 1) * 2048 + lo;
  const int oA2 = (wm * 4 + 2) * 2048 + lo;
  const int oA3 = (wm * 4 + 3) * 2048 + lo;

  v4i E0, E1, E2, E3;
  v4i O0, O1, O2, O3;

#define RD_A(S, B, s)                                                     \
  do {                                                                    \
    S##0 = DSR((B) + oA0 + (s) * 1024);                                   \
    S##1 = DSR((B) + oA1 + (s) * 1024);                                   \
    S##2 = DSR((B) + oA2 + (s) * 1024);                                   \
    S##3 = DSR((B) + oA3 + (s) * 1024);                                   \
  } while (0)

#define MM_GU(S, Gf, Uf)                                                  \
  do {                                                                    \
    __builtin_amdgcn_s_setprio(1);                                        \
    accg[0] = MFMA8(S##0, Gf, accg[0], 0, 0, 0);                          \
    accu[0] = MFMA8(S##0, Uf, accu[0], 0, 0, 0);                          \
    accg[1] = MFMA8(S##1, Gf, accg[1], 0, 0, 0);                          \
    accu[1] = MFMA8(S##1, Uf, accu[1], 0, 0, 0);                          \
    accg[2] = MFMA8(S##2, Gf, accg[2], 0, 0, 0);                          \
    accu[2] = MFMA8(S##2, Uf, accu[2], 0, 0, 0);                          \
    accg[3] = MFMA8(S##3, Gf, accg[3], 0, 0, 0);                          \
    accu[3] = MFMA8(S##3, Uf, accu[3], 0, 0, 0);                          \
    __builtin_amdgcn_s_setprio(0);                                        \
  } while (0)

  char* b0 = lds[0];
  char* b1 = lds[1];
  char* b2 = lds[2];

  v4i GA0, UA0, GA1, UA1;   // B regs for even tiles
  v4i GB0, UB0, GB1, UB1;   // B regs for odd tiles

  {  // Prologue: stage A tiles 0,1; load B(0),B(1); certify; read A s0.
    STAGE_A(b0, 0);
    STAGE_A(b1, 1);
    LDB_GU(GA0, UA0, GA1, UA1, 0);
    LDB_GU(GB0, UB0, GB1, UB1, 1);
    WAITV(0);
    BAR();
    RD_A(E, b0, 0);
  }

  // BODY: P0 {read A s1; stage A(t+2); MM(E) s0} ;
  //       P1 {WAITV(2) certifies A(t+1)+B(t+1); BAR; read A(t+1) s0;
  //           MM(O) s1; load B(t+2) into this parity's regs}
#define BODY_GU(t, G0, U0, G1, U1)                                        \
  do {                                                                    \
    const int ts = ((t) + 2 < NT) ? ((t) + 2) : (NT - 1);                 \
    RD_A(O, b0, 1);                                                       \
    STAGE_A(b2, ts);                                                      \
    LGKM(4);                                                              \
    MM_GU(E, G0, U0);                                                     \
    WAITV(2);                                                             \
    BAR();                                                                \
    RD_A(E, b1, 0);                                                       \
    LGKM(4);                                                              \
    MM_GU(O, G1, U1);                                                     \
    LDB_GU(G0, U0, G1, U1, ts);                                           \
    char* tmp_ = b0; b0 = b1; b1 = b2; b2 = tmp_;                         \
  } while (0)

  for (int tt = 0; tt < NT; tt += 2) {
    BODY_GU(tt,     GA0, UA0, GA1, UA1);
    BODY_GU(tt + 1, GB0, UB0, GB1, UB1);
  }
  WAITV(0);   // drain tail DMAs/loads
#undef BODY_GU
#undef RD_A
#undef MM_GU
#undef STAGE_A
#undef LDB_GU

  // Epilogue (r4/r7-verified): dequant -> SiLU(g)*u -> rint -> clamp -> int8,
  // written in DOWN's shuffled layout [r32][k32=col/32][lane][16B].
  const float ga = *ga_p, ua = *ua_p;
  const int col = n0 + wn * 32 + li32;
  const float gbv = gb[col], ubv = ub[col];
  const int k32q = (n0 >> 5) + wn;
  const int lanehi = ((li32 >> 4) & 1) << 5;
  const int bytelo = li32 & 15;
  const int NKQ = I_DIM / 32;  // 344
#pragma unroll
  for (int mi = 0; mi < 4; ++mi) {
    const int r32q = (m0 >> 5) + wm * 4 + mi;
    char* qbase = Q + ((size_t)(r32q * NKQ + k32q) << 10);
#pragma unroll
    for (int rq = 0; rq < 4; ++rq) {
#pragma unroll
      for (int rr = 0; rr < 4; ++rr) {
        const int rg = rq * 4 + rr;
        const int rowin = kg2 * 4 + rq * 8 + rr;
        float g = (float)accg[mi][rg] * ga + gbv;
        float u = (float)accu[mi][rg] * ua + ubv;
        float x1 = g / (1.0f + expf(-g));
        float x = rintf(x1 * u);
        x = fminf(fmaxf(x, -128.0f), 127.0f);
        qbase[((rowin | lanehi) << 4) + bytelo] = (char)(int)x;
      }
    }
  }
}

// ---------------- down GEMM ----------------
// 256x256 tile, 8 waves (2M x 4N), wave = 128x64, BK=64.
// A via LDS (3x16KB, distance-2); B direct global->reg distance-2.
__global__ __launch_bounds__(512, 2) void gemm_down(
    const char* __restrict__ Qm, const char* __restrict__ Bd,
    const float* __restrict__ da_p, const float* __restrict__ db,
    float* __restrict__ out)
{
  __shared__ char lds[3][16384];
  const int tid = threadIdx.x;
  const int l = tid & 63;
  const int w = tid >> 6;
  const int wm = w >> 2, wn = w & 3;
  const int li32 = l & 31, kg2 = l >> 5;

  const int q8 = 512 / 8;
  int bid = blockIdx.x;
  int wgid = (bid & 7) * q8 + (bid >> 3);
  int st = wgid >> 3, r = wgid & 7;
  int sm = st >> 3, sn = st & 7;
  const int m0 = (sm * 4 + (r & 3)) * 256;
  const int n0 = (sn * 2 + (r >> 2)) * 256;

  const int NK = I_DIM / 32;   // 344
  const int NT = I_DIM / 64;   // 172 K-tiles

  v16i acc[4][2];
#pragma unroll
  for (int i = 0; i < 4; ++i)
#pragma unroll
    for (int n = 0; n < 2; ++n)
#pragma unroll
      for (int j = 0; j < 16; ++j) acc[i][n][j] = 0;

  const int lo = l * 16;
  const char* pA0 = Qm + ((size_t)((m0 >> 5) + w) * NK) * 1024 + lo;
  const int dA0 = w * 2048 + lo;
  const int dA1 = dA0 + 1024;

#define STAGE_A(SB, tt)                                                   \
  do {                                                                    \
    size_t so = (size_t)(tt) * 2048;                                      \
    STG((SB) + dA0, pA0 + so);                                            \
    STG((SB) + dA1, pA0 + so + 1024);                                     \
  } while (0)

  const char* bB0 = rflp(Bd + ((size_t)((n0 >> 5) + wn * 2 + 0) * NK) * 1024);
  const char* bB1 = rflp(Bd + ((size_t)((n0 >> 5) + wn * 2 + 1) * NK) * 1024);

#define LDB_DN(X0, Y0, X1, Y1, tt)                                        \
  do {                                                                    \
    size_t ko = (size_t)(tt) * 2048 + lo;                                 \
    X0 = *(const v4i*)(bB0 + ko);        Y0 = *(const v4i*)(bB1 + ko);    \
    X1 = *(const v4i*)(bB0 + ko + 1024); Y1 = *(const v4i*)(bB1 + ko + 1024);\
    SCHEDB();                                                             \
  } while (0)

  const int oA0 = (wm * 4 + 0) * 2048 + lo;
  const int oA1 = (wm * 4 + 1) * 2048 + lo;
  const int oA2 = (wm * 4 + 2) * 2048 + lo;
  const int oA3 = (wm * 4 + 3) * 2048 + lo;

  v4i E0, E1, E2, E3;
  v4i O0, O1, O2, O3;

#define RD_A(S, B, s)                                                     \
  do {                                                                    \
    S##0 = DSR((B) + oA0 + (s) * 1024);                                   \
    S##1 = DSR((B) + oA1 + (s) * 1024);                                   \
    S##2 = DSR((B) + oA2 + (s) * 1024);                                   \
    S##3 = DSR((B) + oA3 + (s) * 1024);                                   \
  } while (0)

#define MM_DN(S, Bx, By)                                                  \
  do {                                                                    \
    __builtin_amdgcn_s_setprio(1);                                        \
    acc[0][0] = MFMA8(S##0, Bx, acc[0][0], 0, 0, 0);                      \
    acc[0][1] = MFMA8(S##0, By, acc[0][1], 0, 0, 0);                      \
    acc[1][0] = MFMA8(S##1, Bx, acc[1][0], 0, 0, 0);                      \
    acc[1][1] = MFMA8(S##1, By, acc[1][1], 0, 0, 0);                      \
    acc[2][0] = MFMA8(S##2, Bx, acc[2][0], 0, 0, 0);                      \
    acc[2][1] = MFMA8(S##2, By, acc[2][1], 0, 0, 0);                      \
    acc[3][0] = MFMA8(S##3, Bx, acc[3][0], 0, 0, 0);                      \
    acc[3][1] = MFMA8(S##3, By, acc[3][1], 0, 0, 0);                      \
    __builtin_amdgcn_s_setprio(0);                                        \
  } while (0)

  char* b0 = lds[0];
  char* b1 = lds[1];
  char* b2 = lds[2];

  v4i XA0, YA0, XA1, YA1;   // B regs, even tiles
  v4i XB0, YB0, XB1, YB1;   // B regs, odd tiles

  {
    STAGE_A(b0, 0);
    STAGE_A(b1, 1);
    LDB_DN(XA0, YA0, XA1, YA1, 0);
    LDB_DN(XB0, YB0, XB1, YB1, 1);
    WAITV(0);
    BAR();
    RD_A(E, b0, 0);
  }

#define BODY_DN(t, X0, Y0, X1, Y1)                                        \
  do {                                                                    \
    const int ts = ((t) + 2 < NT) ? ((t) + 2) : (NT - 1);                 \
    RD_A(O, b0, 1);                                                       \
    STAGE_A(b2, ts);                                                      \
    LGKM(4);                                                              \
    MM_DN(E, X0, Y0);                                                     \
    WAITV(2);                                                             \
    BAR();                                                                \
    RD_A(E, b1, 0);                                                       \
    LGKM(4);                                                              \
    MM_DN(O, X1, Y1);                                                     \
    LDB_DN(X0, Y0, X1, Y1, ts);                                           \
    char* tmp_ = b0; b0 = b1; b1 = b2; b2 = tmp_;                         \
  } while (0)

  for (int tt = 0; tt < NT; tt += 2) {
    BODY_DN(tt,     XA0, YA0, XA1, YA1);
    BODY_DN(tt + 1, XB0, YB0, XB1, YB1);
  }
  WAITV(0);
#undef BODY_DN
#undef RD_A
#undef MM_DN
#undef STAGE_A
#undef LDB_DN

  const float da = *da_p;
#pragma unroll
  for (int ni = 0; ni < 2; ++ni) {
    const int col = n0 + wn * 64 + ni * 32 + li32;
    const float dbv = db[col];
#pragma unroll
    for (int mi = 0; mi < 4; ++mi) {
      const int rowb = m0 + wm * 128 + mi * 32 + kg2 * 4;
#pragma unroll
      for (int rq = 0; rq < 4; ++rq) {
#pragma unroll
        for (int rr = 0; rr < 4; ++rr)
          out[(size_t)(rowb + rq * 8 + rr) * H_DIM + col] =
              (float)acc[mi][ni][rq * 4 + rr] * da + dbv;
      }
    }
  }
}

extern "C" void kernel_launch(void* const* d_in, const int* in_sizes, int n_in,
                              void* d_out, int out_size, void* d_ws, size_t ws_size,
                              hipStream_t stream) {
  const int*   hs = (const int*)d_in[0];
  const int*   gw = (const int*)d_in[1];
  const float* ga = (const float*)d_in[2];
  const float* gb = (const float*)d_in[3];
  const int*   uw = (const int*)d_in[4];
  const float* ua = (const float*)d_in[5];
  const float* ub = (const float*)d_in[6];
  const int*   dw = (const int*)d_in[7];
  const float* da = (const float*)d_in[8];
  const float* db = (const float*)d_in[9];

  char* ws   = (char*)d_ws;
  char* hidS = ws;                                  // [256][128][64][16] shuffled
  char* gS   = hidS + (size_t)T_DIM * H_DIM;        // [344][128][64][16]
  char* uS   = gS   + (size_t)I_DIM * H_DIM;
  char* dS   = uS   + (size_t)I_DIM * H_DIM;        // [128][344][64][16]
  char* qS   = dS   + (size_t)H_DIM * I_DIM;        // [256][344][64][16]

  pack_shuf<<<2048, 256, 0, stream>>>(hs, hidS, H_DIM / 32, (long)T_DIM * H_DIM / 16);
  pack_shuf<<<2048, 256, 0, stream>>>(gw, gS,   H_DIM / 32, (long)I_DIM * H_DIM / 16);
  pack_shuf<<<2048, 256, 0, stream>>>(uw, uS,   H_DIM / 32, (long)I_DIM * H_DIM / 16);
  pack_shuf<<<2048, 256, 0, stream>>>(dw, dS,   I_DIM / 32, (long)H_DIM * I_DIM / 16);

  gemm_gateup<<<2752, 512, 0, stream>>>(hidS, gS, uS, ga, gb, ua, ub, qS);
  gemm_down<<<512, 512, 0, stream>>>(qS, dS, da, db, (float*)d_out);
}